// Round 3
// baseline (752.806 us; speedup 1.0000x reference)
//
#include <hip/hip_runtime.h>

#define BB 2
#define SS 1024
#define DD 1024
#define HH 16
#define KVH 4
#define HDD 64
#define EE 16
#define II 1408
#define TT (BB*SS)
#define EPS_ 1e-6f

typedef unsigned short u16;
typedef __bf16 bf16x8 __attribute__((ext_vector_type(8)));
typedef float f32x4 __attribute__((ext_vector_type(4)));

__device__ __forceinline__ float wred_sum(float v) {
#pragma unroll
  for (int o = 32; o > 0; o >>= 1) v += __shfl_xor(v, o);
  return v;
}

__device__ __forceinline__ u16 f2b(float f) {
  __bf16 h = (__bf16)f;
  return __builtin_bit_cast(u16, h);
}

__device__ __forceinline__ bf16x8 ld_frag(const u16* p) {
  return __builtin_bit_cast(bf16x8, *(const uint4*)p);
}

// split fp32 into 3 bf16 terms: v ~= b0 + b1 + b2 (24 mantissa bits)
__device__ __forceinline__ void split3f(float v, u16* o0, u16* o1, u16* o2) {
  __bf16 b0 = (__bf16)v; float f0 = (float)b0;
  float r1 = v - f0;     __bf16 b1 = (__bf16)r1; float f1 = (float)b1;
  float r2 = r1 - f1;    __bf16 b2 = (__bf16)r2;
  *o0 = __builtin_bit_cast(u16, b0);
  *o1 = __builtin_bit_cast(u16, b1);
  *o2 = __builtin_bit_cast(u16, b2);
}

// 6-product split-3 accumulate (error ~ fp32)
#define MFMA6(ACC, A0, A1, A2, B0, B1, B2) { \
  f32x4 c_ = ACC; \
  c_ = __builtin_amdgcn_mfma_f32_16x16x32_bf16(A0, B0, c_, 0, 0, 0); \
  c_ = __builtin_amdgcn_mfma_f32_16x16x32_bf16(A0, B1, c_, 0, 0, 0); \
  c_ = __builtin_amdgcn_mfma_f32_16x16x32_bf16(A1, B0, c_, 0, 0, 0); \
  c_ = __builtin_amdgcn_mfma_f32_16x16x32_bf16(A0, B2, c_, 0, 0, 0); \
  c_ = __builtin_amdgcn_mfma_f32_16x16x32_bf16(A1, B1, c_, 0, 0, 0); \
  c_ = __builtin_amdgcn_mfma_f32_16x16x32_bf16(A2, B0, c_, 0, 0, 0); \
  ACC = c_; }

// ---------------- rmsnorm over D=1024 (fp32 out) ----------------
__global__ __launch_bounds__(256) void k_rmsnorm(const float* __restrict__ x,
                                                 const float* __restrict__ w,
                                                 float* __restrict__ out) {
  int row = blockIdx.x, tid = threadIdx.x;
  float4 v = ((const float4*)(x + (size_t)row * DD))[tid];
  float ss = v.x*v.x + v.y*v.y + v.z*v.z + v.w*v.w;
  ss = wred_sum(ss);
  __shared__ float red[4];
  if ((tid & 63) == 0) red[tid >> 6] = ss;
  __syncthreads();
  float tot = red[0] + red[1] + red[2] + red[3];
  float sc = rsqrtf(tot * (1.0f / DD) + EPS_);
  float4 wv = ((const float4*)w)[tid];
  float4 o = make_float4(v.x*sc*wv.x, v.y*sc*wv.y, v.z*sc*wv.z, v.w*sc*wv.w);
  ((float4*)(out + (size_t)row * DD))[tid] = o;
}

// ---------------- rmsnorm with split-3 bf16 output ----------------
__global__ __launch_bounds__(256) void k_rmsnorm_split3(const float* __restrict__ x,
    const float* __restrict__ w, u16* __restrict__ o0, u16* __restrict__ o1,
    u16* __restrict__ o2) {
  int row = blockIdx.x, tid = threadIdx.x;
  float4 v = ((const float4*)(x + (size_t)row * DD))[tid];
  float ss = v.x*v.x + v.y*v.y + v.z*v.z + v.w*v.w;
  ss = wred_sum(ss);
  __shared__ float red[4];
  if ((tid & 63) == 0) red[tid >> 6] = ss;
  __syncthreads();
  float tot = red[0] + red[1] + red[2] + red[3];
  float sc = rsqrtf(tot * (1.0f / DD) + EPS_);
  float4 wv = ((const float4*)w)[tid];
  float vals[4] = {v.x*sc*wv.x, v.y*sc*wv.y, v.z*sc*wv.z, v.w*sc*wv.w};
  ushort4 s0, s1, s2;
  split3f(vals[0], &s0.x, &s1.x, &s2.x);
  split3f(vals[1], &s0.y, &s1.y, &s2.y);
  split3f(vals[2], &s0.z, &s1.z, &s2.z);
  split3f(vals[3], &s0.w, &s1.w, &s2.w);
  size_t base = (size_t)row * DD + tid * 4;
  *(ushort4*)&o0[base] = s0;
  *(ushort4*)&o1[base] = s1;
  *(ushort4*)&o2[base] = s2;
}

// ---------------- fp32 -> bf16 bulk convert ----------------
__global__ __launch_bounds__(256) void k_tobf16(const float* __restrict__ in,
                                                u16* __restrict__ out, int n4) {
  int i = blockIdx.x * 256 + threadIdx.x;
  if (i < n4) {
    float4 v = ((const float4*)in)[i];
    ushort4 o = make_ushort4(f2b(v.x), f2b(v.y), f2b(v.z), f2b(v.w));
    ((ushort4*)out)[i] = o;
  }
}

// ---------------- transpose + split3: W[K][N] fp32 -> WT{0,1,2}[N][K] bf16 ----------------
__global__ __launch_bounds__(256) void k_transpose_split3(const float* __restrict__ Wm,
    u16* __restrict__ T0, u16* __restrict__ T1, u16* __restrict__ T2, int K, int N) {
  int n0 = blockIdx.x * 64, k0 = blockIdx.y * 64;
  __shared__ float tile[64][65];
  int tc = threadIdx.x & 15, tr = threadIdx.x >> 4;
#pragma unroll
  for (int kk = 0; kk < 64; kk += 16) {
    float4 v = *(const float4*)&Wm[(size_t)(k0 + kk + tr) * N + n0 + tc * 4];
    tile[kk + tr][tc*4+0] = v.x; tile[kk + tr][tc*4+1] = v.y;
    tile[kk + tr][tc*4+2] = v.z; tile[kk + tr][tc*4+3] = v.w;
  }
  __syncthreads();
#pragma unroll
  for (int nn = 0; nn < 64; nn += 16) {
    int n = nn + tr;
    ushort4 s0, s1, s2;
    split3f(tile[tc*4+0][n], &s0.x, &s1.x, &s2.x);
    split3f(tile[tc*4+1][n], &s0.y, &s1.y, &s2.y);
    split3f(tile[tc*4+2][n], &s0.z, &s1.z, &s2.z);
    split3f(tile[tc*4+3][n], &s0.w, &s1.w, &s2.w);
    size_t base = (size_t)(n0 + n) * K + k0 + tc * 4;
    *(ushort4*)&T0[base] = s0;
    *(ushort4*)&T1[base] = s1;
    *(ushort4*)&T2[base] = s2;
  }
}

// ---------------- fused QKV GEMM, split-3 MFMA, no LDS ----------------
__global__ __launch_bounds__(256) void k_qkv_mfma(
    const u16* __restrict__ h0, const u16* __restrict__ h1, const u16* __restrict__ h2,
    const u16* __restrict__ wqt0, const u16* __restrict__ wqt1, const u16* __restrict__ wqt2,
    const u16* __restrict__ wkt0, const u16* __restrict__ wkt1, const u16* __restrict__ wkt2,
    const u16* __restrict__ wvt0, const u16* __restrict__ wvt1, const u16* __restrict__ wvt2,
    float* __restrict__ qb, float* __restrict__ kb, float* __restrict__ vb) {
  int nt = blockIdx.x, m0 = blockIdx.y * 128;
  const u16 *B0, *B1, *B2; float* Cm; int Nm, n0;
  if (nt < 16)      { B0=wqt0; B1=wqt1; B2=wqt2; Cm=qb; Nm=1024; n0=nt*64; }
  else if (nt < 20) { B0=wkt0; B1=wkt1; B2=wkt2; Cm=kb; Nm=256;  n0=(nt-16)*64; }
  else              { B0=wvt0; B1=wvt1; B2=wvt2; Cm=vb; Nm=256;  n0=(nt-20)*64; }
  int lane = threadIdx.x & 63, w = threadIdx.x >> 6;
  int wm = (w & 1) * 64, wn = (w >> 1) * 32;
  int lr = lane & 15, lk = (lane >> 4) * 8;
  f32x4 acc[4][2] = {};
  size_t boff[2], aoff[4];
#pragma unroll
  for (int nf = 0; nf < 2; ++nf) boff[nf] = (size_t)(n0 + wn + nf*16 + lr) * 1024 + lk;
#pragma unroll
  for (int fm = 0; fm < 4; ++fm) aoff[fm] = (size_t)(m0 + wm + fm*16 + lr) * 1024 + lk;
  for (int k0 = 0; k0 < 1024; k0 += 32) {
    bf16x8 bf0[2], bf1[2], bf2[2];
#pragma unroll
    for (int nf = 0; nf < 2; ++nf) {
      bf0[nf] = ld_frag(B0 + boff[nf] + k0);
      bf1[nf] = ld_frag(B1 + boff[nf] + k0);
      bf2[nf] = ld_frag(B2 + boff[nf] + k0);
    }
#pragma unroll
    for (int fm = 0; fm < 4; ++fm) {
      bf16x8 a0 = ld_frag(h0 + aoff[fm] + k0);
      bf16x8 a1 = ld_frag(h1 + aoff[fm] + k0);
      bf16x8 a2 = ld_frag(h2 + aoff[fm] + k0);
#pragma unroll
      for (int nf = 0; nf < 2; ++nf) MFMA6(acc[fm][nf], a0, a1, a2, bf0[nf], bf1[nf], bf2[nf])
    }
  }
#pragma unroll
  for (int fm = 0; fm < 4; ++fm)
#pragma unroll
    for (int nf = 0; nf < 2; ++nf)
#pragma unroll
      for (int r = 0; r < 4; ++r) {
        int row = m0 + wm + fm*16 + (lane>>4)*4 + r;
        Cm[(size_t)row * Nm + n0 + wn + nf*16 + lr] = acc[fm][nf][r];
      }
}

// ---------------- per-head q/k rmsnorm + rope -> split-3 bf16 arrays ----------------
__global__ __launch_bounds__(256) void k_qknorm_rope_split(
    const float* __restrict__ qb, const float* __restrict__ kb,
    const float* __restrict__ qnw, const float* __restrict__ knw,
    const float* __restrict__ cosb, const float* __restrict__ sinb,
    u16* __restrict__ q0a, u16* __restrict__ q1a, u16* __restrict__ q2a,
    u16* __restrict__ k0a, u16* __restrict__ k1a, u16* __restrict__ k2a) {
  int tok = blockIdx.x, grp = blockIdx.y;
  int wv = threadIdx.x >> 6, d = threadIdx.x & 63;
  int s = tok & (SS - 1);
  const float* ptr; const float* wn;
  if (grp < 4) { ptr = qb + (size_t)tok * 1024 + (grp * 4 + wv) * 64; wn = qnw; }
  else         { ptr = kb + (size_t)tok * 256 + wv * 64;              wn = knw; }
  float v = ptr[d];
  float ssum = wred_sum(v * v);
  float rms = rsqrtf(ssum * (1.0f / 64.0f) + EPS_);
  float nv = v * rms * wn[d];
  float pn = __shfl_xor(nv, 32);
  float rot = (d < 32) ? -pn : pn;
  float val = nv * cosb[s * 64 + d] + rot * sinb[s * 64 + d];
  u16 a, b, c;
  split3f(val, &a, &b, &c);
  if (grp < 4) {
    size_t idx = (size_t)tok * 1024 + (grp * 4 + wv) * 64 + d;
    q0a[idx] = a; q1a[idx] = b; q2a[idx] = c;
  } else {
    size_t idx = (size_t)tok * 256 + wv * 64 + d;
    k0a[idx] = a; k1a[idx] = b; k2a[idx] = c;
  }
}

// ---------------- v transpose + split3: vb[b*1024+key][kv*64+d] -> vT[bkv*64+d][key] ----------------
__global__ __launch_bounds__(256) void k_splitv(const float* __restrict__ vb,
    u16* __restrict__ t0, u16* __restrict__ t1, u16* __restrict__ t2) {
  int k0 = blockIdx.x * 64, bkv = blockIdx.y;
  int b = bkv >> 2, kv = bkv & 3;
  __shared__ float tile[64][65];
  int tc = threadIdx.x & 15, tr = threadIdx.x >> 4;
#pragma unroll
  for (int kk = 0; kk < 64; kk += 16) {
    float4 v = *(const float4*)&vb[(size_t)(b * 1024 + k0 + kk + tr) * 256 + kv * 64 + tc * 4];
    tile[kk + tr][tc*4+0] = v.x; tile[kk + tr][tc*4+1] = v.y;
    tile[kk + tr][tc*4+2] = v.z; tile[kk + tr][tc*4+3] = v.w;
  }
  __syncthreads();
#pragma unroll
  for (int dd = 0; dd < 64; dd += 16) {
    int d = dd + tr;
    ushort4 s0, s1, s2;
    split3f(tile[tc*4+0][d], &s0.x, &s1.x, &s2.x);
    split3f(tile[tc*4+1][d], &s0.y, &s1.y, &s2.y);
    split3f(tile[tc*4+2][d], &s0.z, &s1.z, &s2.z);
    split3f(tile[tc*4+3][d], &s0.w, &s1.w, &s2.w);
    size_t base = (size_t)(bkv * 64 + d) * 1024 + k0 + tc * 4;
    *(ushort4*)&t0[base] = s0;
    *(ushort4*)&t1[base] = s1;
    *(ushort4*)&t2[base] = s2;
  }
}

// ---------------- scores, split-3 MFMA, no LDS ----------------
__global__ __launch_bounds__(256) void k_scores_mfma(
    const u16* __restrict__ q0a, const u16* __restrict__ q1a, const u16* __restrict__ q2a,
    const u16* __restrict__ k0a, const u16* __restrict__ k1a, const u16* __restrict__ k2a,
    float* __restrict__ sc, int bh0) {
  int kt = blockIdx.x, qt = blockIdx.y;
  if (kt > 2 * qt + 1) return;
  int bh = bh0 + blockIdx.z, b = bh >> 4, hh = bh & 15, kv = hh >> 2;
  int q0 = qt * 128, kk0 = kt * 64;
  int lane = threadIdx.x & 63, w = threadIdx.x >> 6;
  int wm = (w & 1) * 64, wn = (w >> 1) * 32;
  int lr = lane & 15, lk = (lane >> 4) * 8;
  f32x4 acc[4][2] = {};
  size_t ab = (size_t)(b * 1024 + q0 + wm + lr) * 1024 + hh * 64 + lk;
  size_t bb = (size_t)(b * 1024 + kk0 + wn + lr) * 256 + kv * 64 + lk;
#pragma unroll
  for (int d0 = 0; d0 < 64; d0 += 32) {
    bf16x8 bf0[2], bf1[2], bf2[2];
#pragma unroll
    for (int nf = 0; nf < 2; ++nf) {
      size_t o = bb + (size_t)nf * 16 * 256 + d0;
      bf0[nf] = ld_frag(k0a + o); bf1[nf] = ld_frag(k1a + o); bf2[nf] = ld_frag(k2a + o);
    }
#pragma unroll
    for (int fm = 0; fm < 4; ++fm) {
      size_t o = ab + (size_t)fm * 16 * 1024 + d0;
      bf16x8 a0 = ld_frag(q0a + o), a1 = ld_frag(q1a + o), a2 = ld_frag(q2a + o);
#pragma unroll
      for (int nf = 0; nf < 2; ++nf) MFMA6(acc[fm][nf], a0, a1, a2, bf0[nf], bf1[nf], bf2[nf])
    }
  }
  float* srow = sc + (size_t)blockIdx.z * SS * SS;
#pragma unroll
  for (int fm = 0; fm < 4; ++fm)
#pragma unroll
    for (int nf = 0; nf < 2; ++nf)
#pragma unroll
      for (int r = 0; r < 4; ++r) {
        int row = q0 + wm + fm*16 + (lane>>4)*4 + r;
        srow[(size_t)row * SS + kk0 + wn + nf*16 + lr] = acc[fm][nf][r] * 0.125f;
      }
}

// ---------------- row softmax -> split-3 bf16 P ----------------
__global__ __launch_bounds__(256) void k_softmax_split(const float* __restrict__ sc,
    u16* __restrict__ P0, u16* __restrict__ P1, u16* __restrict__ P2) {
  int q = blockIdx.x, z = blockIdx.y, tid = threadIdx.x;
  const float* row = sc + (size_t)z * SS * SS + (size_t)q * SS;
  int n = q + 1;
  float v[4];
  float m = -3.4e38f;
#pragma unroll
  for (int j = 0; j < 4; ++j) {
    int i = tid + j * 256;
    v[j] = (i < n) ? row[i] : -3.4e38f;
    m = fmaxf(m, v[j]);
  }
#pragma unroll
  for (int o = 32; o > 0; o >>= 1) m = fmaxf(m, __shfl_xor(m, o));
  __shared__ float redm[4], reds[4];
  if ((tid & 63) == 0) redm[tid >> 6] = m;
  __syncthreads();
  m = fmaxf(fmaxf(redm[0], redm[1]), fmaxf(redm[2], redm[3]));
  float e[4];
  float l = 0.f;
#pragma unroll
  for (int j = 0; j < 4; ++j) {
    int i = tid + j * 256;
    e[j] = (i < n) ? __expf(v[j] - m) : 0.f;
    l += e[j];
  }
  l = wred_sum(l);
  if ((tid & 63) == 0) reds[tid >> 6] = l;
  __syncthreads();
  l = reds[0] + reds[1] + reds[2] + reds[3];
  float inv = 1.0f / l;
  size_t base = (size_t)z * 1048576 + (size_t)q * 1024;
#pragma unroll
  for (int j = 0; j < 4; ++j) {
    int i = tid + j * 256;
    u16 a, bb, c;
    split3f(e[j] * inv, &a, &bb, &c);
    P0[base + i] = a; P1[base + i] = bb; P2[base + i] = c;
  }
}

// ---------------- PV, split-3 MFMA, no LDS; writes split-3 attn ----------------
__global__ __launch_bounds__(256) void k_pv_mfma(
    const u16* __restrict__ P0, const u16* __restrict__ P1, const u16* __restrict__ P2,
    const u16* __restrict__ vt0, const u16* __restrict__ vt1, const u16* __restrict__ vt2,
    u16* __restrict__ at0, u16* __restrict__ at1, u16* __restrict__ at2, int bh0) {
  int qt = blockIdx.x, z = blockIdx.y;
  int bh = bh0 + z, b = bh >> 4, hh = bh & 15, kv = hh >> 2;
  int bkv = b * 4 + kv;
  int q0 = qt * 128;
  int lane = threadIdx.x & 63, w = threadIdx.x >> 6;
  int wm = (w & 1) * 64, wn = (w >> 1) * 32;
  int lr = lane & 15, lk = (lane >> 4) * 8;
  f32x4 acc[4][2] = {};
  size_t pz = (size_t)z * 1048576;
  size_t aoff[4], boff[2];
#pragma unroll
  for (int fm = 0; fm < 4; ++fm) aoff[fm] = pz + (size_t)(q0 + wm + fm*16 + lr) * 1024 + lk;
#pragma unroll
  for (int nf = 0; nf < 2; ++nf) boff[nf] = (size_t)(bkv * 64 + wn + nf*16 + lr) * 1024 + lk;
  int kend = q0 + 128;
  for (int k0 = 0; k0 < kend; k0 += 32) {
    bf16x8 bf0[2], bf1[2], bf2[2];
#pragma unroll
    for (int nf = 0; nf < 2; ++nf) {
      bf0[nf] = ld_frag(vt0 + boff[nf] + k0);
      bf1[nf] = ld_frag(vt1 + boff[nf] + k0);
      bf2[nf] = ld_frag(vt2 + boff[nf] + k0);
    }
#pragma unroll
    for (int fm = 0; fm < 4; ++fm) {
      bf16x8 a0 = ld_frag(P0 + aoff[fm] + k0);
      bf16x8 a1 = ld_frag(P1 + aoff[fm] + k0);
      bf16x8 a2 = ld_frag(P2 + aoff[fm] + k0);
#pragma unroll
      for (int nf = 0; nf < 2; ++nf) MFMA6(acc[fm][nf], a0, a1, a2, bf0[nf], bf1[nf], bf2[nf])
    }
  }
#pragma unroll
  for (int fm = 0; fm < 4; ++fm)
#pragma unroll
    for (int nf = 0; nf < 2; ++nf)
#pragma unroll
      for (int r = 0; r < 4; ++r) {
        int row = q0 + wm + fm*16 + (lane>>4)*4 + r;
        size_t idx = (size_t)(b * 1024 + row) * 1024 + hh * 64 + wn + nf*16 + lr;
        u16 a, bb, c;
        split3f(acc[fm][nf][r], &a, &bb, &c);
        at0[idx] = a; at1[idx] = bb; at2[idx] = c;
      }
}

// ---------------- Wo GEMM + residual, split-3 MFMA ----------------
__global__ __launch_bounds__(256) void k_wo_mfma(
    const u16* __restrict__ at0, const u16* __restrict__ at1, const u16* __restrict__ at2,
    const u16* __restrict__ wot0, const u16* __restrict__ wot1, const u16* __restrict__ wot2,
    const float* __restrict__ x, float* __restrict__ x2) {
  int n0 = blockIdx.x * 64, m0 = blockIdx.y * 128;
  int lane = threadIdx.x & 63, w = threadIdx.x >> 6;
  int wm = (w & 1) * 64, wn = (w >> 1) * 32;
  int lr = lane & 15, lk = (lane >> 4) * 8;
  f32x4 acc[4][2] = {};
  size_t aoff[4], boff[2];
#pragma unroll
  for (int fm = 0; fm < 4; ++fm) aoff[fm] = (size_t)(m0 + wm + fm*16 + lr) * 1024 + lk;
#pragma unroll
  for (int nf = 0; nf < 2; ++nf) boff[nf] = (size_t)(n0 + wn + nf*16 + lr) * 1024 + lk;
  for (int k0 = 0; k0 < 1024; k0 += 32) {
    bf16x8 bf0[2], bf1[2], bf2[2];
#pragma unroll
    for (int nf = 0; nf < 2; ++nf) {
      bf0[nf] = ld_frag(wot0 + boff[nf] + k0);
      bf1[nf] = ld_frag(wot1 + boff[nf] + k0);
      bf2[nf] = ld_frag(wot2 + boff[nf] + k0);
    }
#pragma unroll
    for (int fm = 0; fm < 4; ++fm) {
      bf16x8 a0 = ld_frag(at0 + aoff[fm] + k0);
      bf16x8 a1 = ld_frag(at1 + aoff[fm] + k0);
      bf16x8 a2 = ld_frag(at2 + aoff[fm] + k0);
#pragma unroll
      for (int nf = 0; nf < 2; ++nf) MFMA6(acc[fm][nf], a0, a1, a2, bf0[nf], bf1[nf], bf2[nf])
    }
  }
#pragma unroll
  for (int fm = 0; fm < 4; ++fm)
#pragma unroll
    for (int nf = 0; nf < 2; ++nf)
#pragma unroll
      for (int r = 0; r < 4; ++r) {
        int row = m0 + wm + fm*16 + (lane>>4)*4 + r;
        int col = n0 + wn + nf*16 + lr;
        x2[(size_t)row * 1024 + col] = acc[fm][nf][r] + x[(size_t)row * 1024 + col];
      }
}

// ---------------- router logits (identical arithmetic to r1/r2) ----------------
__global__ __launch_bounds__(256) void k_logits(const float* __restrict__ tb,
    const float* __restrict__ rw, float* __restrict__ logits) {
  int tok = blockIdx.x, tid = threadIdx.x;
  __shared__ __align__(16) float tl[1024];
  __shared__ float part[16][16];
  ((float4*)tl)[tid] = ((const float4*)(tb + (size_t)tok * DD))[tid];
  __syncthreads();
  int e = tid & 15, ch = tid >> 4;
  float p = 0.f;
#pragma unroll 8
  for (int j = 0; j < 64; ++j) p = fmaf(tl[ch * 64 + j], rw[(ch * 64 + j) * EE + e], p);
  part[ch][e] = p;
  __syncthreads();
  if (tid < 16) {
    float s = 0.f;
#pragma unroll
    for (int c = 0; c < 16; ++c) s += part[c][tid];
    logits[(size_t)tok * EE + tid] = s;
  }
}

// ---------------- route: softmax16 + top2 per thread; few atomics ----------------
__global__ __launch_bounds__(256) void k_route(const float* __restrict__ logits,
    int* __restrict__ cnt, int* __restrict__ listTok, int* __restrict__ tokslot,
    float* __restrict__ topw, float* __restrict__ psum) {
  int tid = threadIdx.x;
  int tok = blockIdx.x * 256 + tid;
  __shared__ int lcnt[16], gbase[16];
  __shared__ float lps[16];
  if (tid < 16) { lcnt[tid] = 0; lps[tid] = 0.f; }
  __syncthreads();
  float pr[16];
#pragma unroll
  for (int g = 0; g < 4; ++g) {
    float4 v = *(const float4*)&logits[(size_t)tok * EE + g * 4];
    pr[g*4+0] = v.x; pr[g*4+1] = v.y; pr[g*4+2] = v.z; pr[g*4+3] = v.w;
  }
  float mx = pr[0];
#pragma unroll
  for (int i = 1; i < 16; ++i) mx = fmaxf(mx, pr[i]);
  float s = 0.f;
#pragma unroll
  for (int i = 0; i < 16; ++i) { pr[i] = __expf(pr[i] - mx); s += pr[i]; }
  float inv = 1.0f / s;
#pragma unroll
  for (int i = 0; i < 16; ++i) pr[i] *= inv;
  int i1 = 0; float v1 = pr[0];
#pragma unroll
  for (int i = 1; i < 16; ++i) if (pr[i] > v1) { v1 = pr[i]; i1 = i; }
  int i2 = -1; float v2 = -1.f;
#pragma unroll
  for (int i = 0; i < 16; ++i) if (i != i1 && pr[i] > v2) { v2 = pr[i]; i2 = i; }
  float wsum = v1 + v2;
  int lp1 = atomicAdd(&lcnt[i1], 1);
  int lp2 = atomicAdd(&lcnt[i2], 1);
#pragma unroll
  for (int e = 0; e < 16; ++e) {
    float v = wred_sum(pr[e]);
    if ((tid & 63) == 0) atomicAdd(&lps[e], v);
  }
  __syncthreads();
  if (tid < 16) {
    gbase[tid] = atomicAdd(&cnt[tid], lcnt[tid]);
    atomicAdd(&psum[tid], lps[tid]);
  }
  __syncthreads();
  int p1 = gbase[i1] + lp1, p2 = gbase[i2] + lp2;
  listTok[i1 * 2048 + p1] = tok;
  listTok[i2 * 2048 + p2] = tok;
  tokslot[tok * 2 + 0] = i1 * 2048 + p1;
  tokslot[tok * 2 + 1] = i2 * 2048 + p2;
  topw[tok * 2 + 0] = v1 / wsum;
  topw[tok * 2 + 1] = v2 / wsum;
}

__global__ void k_zero(int* cnt, float* psum) {
  int t = threadIdx.x;
  if (t < 16) { cnt[t] = 0; psum[t] = 0.f; }
}

__global__ void k_prefix(const int* __restrict__ cnt, int* __restrict__ offs) {
  if (threadIdx.x == 0) {
    int s = 0;
    for (int e = 0; e < 16; ++e) { offs[e] = s; s += cnt[e]; }
  }
}

// ---------------- MoE gate/up MFMA (unchanged from r2) ----------------
__global__ __launch_bounds__(256) void k_gu_mfma(const u16* __restrict__ tbh,
    const float* __restrict__ wg, const float* __restrict__ wu,
    const int* __restrict__ cnt, const int* __restrict__ offs,
    const int* __restrict__ listTok, u16* __restrict__ act) {
  int e = blockIdx.z;
  int ce = cnt[e];
  int m0 = blockIdx.y * 128;
  if (m0 >= ce) return;
  int n0 = blockIdx.x * 64;
  __shared__ __align__(16) u16 Ah[128][56];
  __shared__ __align__(16) u16 Gh[64][56];
  __shared__ __align__(16) u16 Uh[64][56];
  __shared__ int rows[128];
  int tid = threadIdx.x;
  if (tid < 128) {
    int m = m0 + tid;
    rows[tid] = listTok[e * 2048 + (m < ce ? m : ce - 1)];
  }
  __syncthreads();
  int s_arow = tid >> 1, s_acol = (tid & 1) * 16;
  int s_nc = (tid & 31) * 2, s_kg = (tid >> 5) * 4;
  const float* wge = wg + (size_t)e * DD * II + n0;
  const float* wue = wu + (size_t)e * DD * II + n0;
  const u16* ap = tbh + (size_t)rows[s_arow] * DD + s_acol;
  int lane = tid & 63, w = tid >> 6;
  int wm = (w & 1) * 64, wn = (w >> 1) * 32;
  int lr = lane & 15, lk = (lane >> 4) * 8;
  f32x4 accg[4][2] = {};
  f32x4 accu[4][2] = {};
  for (int k0 = 0; k0 < DD; k0 += 32) {
    uint4 av0 = *(const uint4*)(ap + k0);
    uint4 av1 = *(const uint4*)(ap + k0 + 8);
    float2 g0 = *(const float2*)&wge[(size_t)(k0 + s_kg + 0) * II + s_nc];
    float2 g1 = *(const float2*)&wge[(size_t)(k0 + s_kg + 1) * II + s_nc];
    float2 g2 = *(const float2*)&wge[(size_t)(k0 + s_kg + 2) * II + s_nc];
    float2 g3 = *(const float2*)&wge[(size_t)(k0 + s_kg + 3) * II + s_nc];
    float2 u0 = *(const float2*)&wue[(size_t)(k0 + s_kg + 0) * II + s_nc];
    float2 u1 = *(const float2*)&wue[(size_t)(k0 + s_kg + 1) * II + s_nc];
    float2 u2 = *(const float2*)&wue[(size_t)(k0 + s_kg + 2) * II + s_nc];
    float2 u3 = *(const float2*)&wue[(size_t)(k0 + s_kg + 3) * II + s_nc];
    *(uint4*)&Ah[s_arow][s_acol]     = av0;
    *(uint4*)&Ah[s_arow][s_acol + 8] = av1;
    *(ushort4*)&Gh[s_nc][s_kg]     = make_ushort4(f2b(g0.x), f2b(g1.x), f2b(g2.x), f2b(g3.x));
    *(ushort4*)&Gh[s_nc + 1][s_kg] = make_ushort4(f2b(g0.y), f2b(g1.y), f2b(g2.y), f2b(g3.y));
    *(ushort4*)&Uh[s_nc][s_kg]     = make_ushort4(f2b(u0.x), f2b(u1.x), f2b(u2.x), f2b(u3.x));
    *(ushort4*)&Uh[s_nc + 1][s_kg] = make_ushort4(f2b(u0.y), f2b(u1.y), f2b(u2.y), f2b(u3.y));
    __syncthreads();
    bf16x8 af[4];
#pragma unroll
    for (int fm = 0; fm < 4; ++fm) af[fm] = ld_frag(&Ah[wm + fm*16 + lr][lk]);
#pragma unroll
    for (int nf = 0; nf < 2; ++nf) {
      bf16x8 bg = ld_frag(&Gh[wn + nf*16 + lr][lk]);
      bf16x8 bu = ld_frag(&Uh[wn + nf*16 + lr][lk]);
#pragma unroll
      for (int fm = 0; fm < 4; ++fm) {
        accg[fm][nf] = __builtin_amdgcn_mfma_f32_16x16x32_bf16(af[fm], bg, accg[fm][nf], 0, 0, 0);
        accu[fm][nf] = __builtin_amdgcn_mfma_f32_16x16x32_bf16(af[fm], bu, accu[fm][nf], 0, 0, 0);
      }
    }
    __syncthreads();
  }
  int ob = offs[e];
#pragma unroll
  for (int fm = 0; fm < 4; ++fm)
#pragma unroll
    for (int nf = 0; nf < 2; ++nf)
#pragma unroll
      for (int r = 0; r < 4; ++r) {
        int m = m0 + wm + fm*16 + (lane >> 4) * 4 + r;
        if (m < ce) {
          float g = accg[fm][nf][r], u = accu[fm][nf][r];
          float sv = (g / (1.f + __expf(-g))) * u;
          act[(size_t)(ob + m) * II + n0 + wn + nf*16 + (lane & 15)] = f2b(sv);
        }
      }
}

// ---------------- MoE down MFMA (unchanged from r2) ----------------
__global__ __launch_bounds__(256) void k_down_mfma(const u16* __restrict__ act,
    const float* __restrict__ wd, const int* __restrict__ cnt, const int* __restrict__ offs,
    float* __restrict__ eo) {
  int e = blockIdx.z;
  int ce = cnt[e];
  int m0 = blockIdx.y * 128;
  if (m0 >= ce) return;
  int n0 = blockIdx.x * 64;
  __shared__ __align__(16) u16 Ah[128][56];
  __shared__ __align__(16) u16 Bh[64][56];
  int tid = threadIdx.x;
  int ob = offs[e];
  int s_arow = tid >> 1, s_acol = (tid & 1) * 16;
  int s_nc = (tid & 31) * 2, s_kg = (tid >> 5) * 4;
  int mrow = m0 + s_arow; if (mrow >= ce) mrow = ce - 1;
  const u16* ap = act + (size_t)(ob + mrow) * II + s_acol;
  const float* wde = wd + (size_t)e * II * DD + n0;
  int lane = tid & 63, w = tid >> 6;
  int wm = (w & 1) * 64, wn = (w >> 1) * 32;
  int lr = lane & 15, lk = (lane >> 4) * 8;
  f32x4 acc[4][2] = {};
  for (int k0 = 0; k0 < II; k0 += 32) {
    uint4 av0 = *(const uint4*)(ap + k0);
    uint4 av1 = *(const uint4*)(ap + k0 + 8);
    float2 b0 = *(const float2*)&wde[(size_t)(k0 + s_kg + 0) * DD + s_nc];
    float2 b1 = *(const float2*)&wde[(size_t)(k0 + s_kg + 1) * DD + s_nc];
    float2 b2 = *(const float2*)&wde[(size_t)(k0 + s_kg + 2) * DD + s_nc];
    float2 b3 = *(const float2*)&wde[(size_t)(k0 + s_kg + 3) * DD + s_nc];
    *(uint4*)&Ah[s_arow][s_acol]     = av0;
    *(uint4*)&Ah[s_arow][s_acol + 8] = av1;
    *(ushort4*)&Bh[s_nc][s_kg]     = make_ushort4(f2b(b0.x), f2b(b1.x), f2b(b2.x), f2b(b3.x));
    *(ushort4*)&Bh[s_nc + 1][s_kg] = make_ushort4(f2b(b0.y), f2b(b1.y), f2b(b2.y), f2b(b3.y));
    __syncthreads();
    bf16x8 af[4];
#pragma unroll
    for (int fm = 0; fm < 4; ++fm) af[fm] = ld_frag(&Ah[wm + fm*16 + lr][lk]);
#pragma unroll
    for (int nf = 0; nf < 2; ++nf) {
      bf16x8 bb = ld_frag(&Bh[wn + nf*16 + lr][lk]);
#pragma unroll
      for (int fm = 0; fm < 4; ++fm)
        acc[fm][nf] = __builtin_amdgcn_mfma_f32_16x16x32_bf16(af[fm], bb, acc[fm][nf], 0, 0, 0);
    }
    __syncthreads();
  }
#pragma unroll
  for (int fm = 0; fm < 4; ++fm)
#pragma unroll
    for (int nf = 0; nf < 2; ++nf)
#pragma unroll
      for (int r = 0; r < 4; ++r) {
        int m = m0 + wm + fm*16 + (lane >> 4) * 4 + r;
        if (m < ce)
          eo[(size_t)(ob + m) * DD + n0 + wn + nf*16 + (lane & 15)] = acc[fm][nf][r];
      }
}

// ---------------- final combine ----------------
__global__ __launch_bounds__(256) void k_final(const float* __restrict__ x2,
    const float* __restrict__ eo, const int* __restrict__ tokslot,
    const float* __restrict__ topw, const int* __restrict__ offs, float* __restrict__ out) {
  int tok = blockIdx.x, tid = threadIdx.x;
  int c0 = tokslot[tok * 2], c1 = tokslot[tok * 2 + 1];
  int s0 = offs[c0 >> 11] + (c0 & 2047);
  int s1 = offs[c1 >> 11] + (c1 & 2047);
  float w0 = topw[tok * 2], w1 = topw[tok * 2 + 1];
  float4 a = ((const float4*)(x2 + (size_t)tok * DD))[tid];
  float4 e0 = ((const float4*)(eo + (size_t)s0 * DD))[tid];
  float4 e1 = ((const float4*)(eo + (size_t)s1 * DD))[tid];
  float4 o = make_float4(a.x + w0*e0.x + w1*e1.x, a.y + w0*e0.y + w1*e1.y,
                         a.z + w0*e0.z + w1*e1.z, a.w + w0*e0.w + w1*e1.w);
  ((float4*)(out + (size_t)tok * DD))[tid] = o;
}

__global__ void k_aux(const int* __restrict__ cnt, const float* __restrict__ psum,
                      float* __restrict__ out) {
  if (threadIdx.x == 0) {
    float a = 0.f;
    for (int e = 0; e < 16; ++e)
      a += ((float)cnt[e] * (1.0f / 4096.0f)) * (psum[e] * (1.0f / 2048.0f));
    out[(size_t)TT * DD] = 16.0f * a;
  }
}

extern "C" void kernel_launch(void* const* d_in, const int* in_sizes, int n_in,
                              void* d_out, int out_size, void* d_ws, size_t ws_size,
                              hipStream_t stream) {
  const float* x    = (const float*)d_in[0];
  const float* cosb = (const float*)d_in[1];
  const float* sinb = (const float*)d_in[2];
  const float* ln1w = (const float*)d_in[3];
  const float* wq   = (const float*)d_in[4];
  const float* wk   = (const float*)d_in[5];
  const float* wv   = (const float*)d_in[6];
  const float* wo   = (const float*)d_in[7];
  const float* qnw  = (const float*)d_in[8];
  const float* knw  = (const float*)d_in[9];
  const float* ln2w = (const float*)d_in[10];
  const float* rw   = (const float*)d_in[11];
  const float* wg   = (const float*)d_in[12];
  const float* wu   = (const float*)d_in[13];
  const float* wd   = (const float*)d_in[14];
  float* out = (float*)d_out;

  float* W = (float*)d_ws;
  int*   cnt     = (int*)W;
  int*   offs    = (int*)(W + 16);
  float* psum    = W + 32;
  int*   tokslot = (int*)(W + 64);
  float* topw    = W + 4160;
  int*   listTok = (int*)(W + 8256);
  float* logits  = W + 41024;
  size_t o = 81920;
#define ALLOC_F(name, n)   float* name = W + o; o += (n);
#define ALLOC_U16(name, n) u16* name = (u16*)(W + o); o += (n) / 2;
  ALLOC_U16(h0, 2097152) ALLOC_U16(h1, 2097152) ALLOC_U16(h2, 2097152)
  ALLOC_F(qb, 2097152) ALLOC_F(kb, 524288) ALLOC_F(vb, 524288)
  ALLOC_U16(wqt0, 1048576) ALLOC_U16(wqt1, 1048576) ALLOC_U16(wqt2, 1048576)
  ALLOC_U16(wkt0, 262144) ALLOC_U16(wkt1, 262144) ALLOC_U16(wkt2, 262144)
  ALLOC_U16(wvt0, 262144) ALLOC_U16(wvt1, 262144) ALLOC_U16(wvt2, 262144)
  ALLOC_U16(wot0, 1048576) ALLOC_U16(wot1, 1048576) ALLOC_U16(wot2, 1048576)
  ALLOC_U16(qs0, 2097152) ALLOC_U16(qs1, 2097152) ALLOC_U16(qs2, 2097152)
  ALLOC_U16(ks0, 524288) ALLOC_U16(ks1, 524288) ALLOC_U16(ks2, 524288)
  ALLOC_U16(vt0, 524288) ALLOC_U16(vt1, 524288) ALLOC_U16(vt2, 524288)
  ALLOC_U16(at0, 2097152) ALLOC_U16(at1, 2097152) ALLOC_U16(at2, 2097152)
  ALLOC_F(x2, 2097152) ALLOC_F(tb, 2097152)
  ALLOC_U16(tbh, 2097152)
  ALLOC_U16(act, 5767168)
  ALLOC_F(eo, 4194304)
  long avail = (long)(ws_size / 4) - (long)o;
  int NC = (int)(avail / 2621440L);   // per chunk: sc 1M + P0..2 1.5M floats
  if (NC > 32) NC = 32;
  if (NC < 1) NC = 1;
  ALLOC_U16(P0, (size_t)NC * 1048576) ALLOC_U16(P1, (size_t)NC * 1048576)
  ALLOC_U16(P2, (size_t)NC * 1048576)
  ALLOC_F(sc, (size_t)NC * 1048576)
#undef ALLOC_F
#undef ALLOC_U16

  k_zero<<<1, 64, 0, stream>>>(cnt, psum);
  k_rmsnorm_split3<<<TT, 256, 0, stream>>>(x, ln1w, h0, h1, h2);
  k_transpose_split3<<<dim3(16, 16), 256, 0, stream>>>(wq, wqt0, wqt1, wqt2, 1024, 1024);
  k_transpose_split3<<<dim3(4, 16), 256, 0, stream>>>(wk, wkt0, wkt1, wkt2, 1024, 256);
  k_transpose_split3<<<dim3(4, 16), 256, 0, stream>>>(wv, wvt0, wvt1, wvt2, 1024, 256);
  k_transpose_split3<<<dim3(16, 16), 256, 0, stream>>>(wo, wot0, wot1, wot2, 1024, 1024);
  k_qkv_mfma<<<dim3(24, 16), 256, 0, stream>>>(h0, h1, h2,
      wqt0, wqt1, wqt2, wkt0, wkt1, wkt2, wvt0, wvt1, wvt2, qb, kb, vb);
  k_qknorm_rope_split<<<dim3(TT, 5), 256, 0, stream>>>(qb, kb, qnw, knw, cosb, sinb,
      qs0, qs1, qs2, ks0, ks1, ks2);
  k_splitv<<<dim3(16, 8), 256, 0, stream>>>(vb, vt0, vt1, vt2);
  for (int bh0 = 0; bh0 < 32; bh0 += NC) {
    int nc = 32 - bh0; if (nc > NC) nc = NC;
    k_scores_mfma<<<dim3(16, 8, nc), 256, 0, stream>>>(qs0, qs1, qs2, ks0, ks1, ks2, sc, bh0);
    k_softmax_split<<<dim3(SS, nc), 256, 0, stream>>>(sc, P0, P1, P2);
    k_pv_mfma<<<dim3(8, nc), 256, 0, stream>>>(P0, P1, P2, vt0, vt1, vt2, at0, at1, at2, bh0);
  }
  k_wo_mfma<<<dim3(16, 16), 256, 0, stream>>>(at0, at1, at2, wot0, wot1, wot2, x, x2);
  k_rmsnorm<<<TT, 256, 0, stream>>>(x2, ln2w, tb);
  k_tobf16<<<(TT * DD / 4 + 255) / 256, 256, 0, stream>>>(tb, tbh, TT * DD / 4);
  k_logits<<<TT, 256, 0, stream>>>(tb, rw, logits);
  k_route<<<TT / 256, 256, 0, stream>>>(logits, cnt, listTok, tokslot, topw, psum);
  k_prefix<<<1, 1, 0, stream>>>(cnt, offs);
  k_gu_mfma<<<dim3(22, 16, 16), 256, 0, stream>>>(tbh, wg, wu, cnt, offs, listTok, act);
  k_down_mfma<<<dim3(16, 16, 16), 256, 0, stream>>>(act, wd, cnt, offs, eo);
  k_final<<<TT, 256, 0, stream>>>(x2, eo, tokslot, topw, offs, out);
  k_aux<<<1, 1, 0, stream>>>(cnt, psum, out);
}